// Round 8
// baseline (26783.881 us; speedup 1.0000x reference)
//
#include <hip/hip_runtime.h>

#define B_SZ 1024
#define S_LEN 128
#define HDIM 512
#define ZDIM 2048   // 4*H
#define INV 16
#define OUTV 9
#define MAXLEN 48
#define MROWS 16    // batch rows per persistent block
#define PADK 520    // padded LDS row stride (u16) -> 2-way (free) bank pattern

typedef unsigned short u16;
typedef __bf16 bf16x8 __attribute__((ext_vector_type(8)));
typedef float f32x4 __attribute__((ext_vector_type(4)));

__device__ __forceinline__ float bf2f(u16 u) {
    union { float f; unsigned int i; } x; x.i = ((unsigned int)u) << 16; return x.f;
}
__device__ __forceinline__ u16 f2bf(float f) {
    union { float f; unsigned int i; } x; x.f = f;
    unsigned int r = (x.i + 0x7fffu + ((x.i >> 16) & 1u)) >> 16;
    return (u16)r;
}
__device__ __forceinline__ float ldf(const void* p, long i, int isf32) {
    return isf32 ? ((const float*)p)[i] : bf2f(((const u16*)p)[i]);
}
__device__ __forceinline__ float sigm(float x) { return 1.0f / (1.0f + expf(-x)); }

// Detect input dtype (fp32 vs bf16) from weight bit patterns.
__global__ void detect_k(const u16* __restrict__ wh, int* __restrict__ flag)
{
    __shared__ int s;
    if (threadIdx.x == 0) s = 0;
    __syncthreads();
    int any = 0;
    for (int i = threadIdx.x; i < 16384; i += 256)
        if (((wh[i] >> 7) & 0xFF) >= 0x7F) any = 1;
    if (any) atomicOr(&s, 1);
    __syncthreads();
    if (threadIdx.x == 0) *flag = s;
}

// Wh [512][2048] (bf16 or fp32) -> WhT hi/lo [2048][512] bf16
__global__ void transpose_k(const void* __restrict__ src, u16* __restrict__ dhi,
                            u16* __restrict__ dlo, const int* __restrict__ dflag)
{
    __shared__ float tile[32][33];
    const int f32 = *dflag;
    const int tx = threadIdx.x & 31, ty = threadIdx.x >> 5;
    const int n0 = blockIdx.x * 32;
    const int k0 = blockIdx.y * 32;
#pragma unroll
    for (int i = 0; i < 32; i += 8)
        tile[ty + i][tx] = ldf(src, (long)(k0 + ty + i) * ZDIM + n0 + tx, f32);
    __syncthreads();
#pragma unroll
    for (int i = 0; i < 32; i += 8) {
        const float v = tile[tx][ty + i];
        const u16 hi = f2bf(v);
        const long o = (long)(n0 + ty + i) * HDIM + k0 + tx;
        dhi[o] = hi;
        dlo[o] = f2bf(v - bf2f(hi));
    }
}

// xz[v][n] = bias[n] + sum_k E[v][k] * Wi[k][n]
__global__ void precompute_xz(const void* __restrict__ E, const void* __restrict__ Wi,
                              const void* __restrict__ bias, float* __restrict__ xz,
                              int K, const int* __restrict__ dflag)
{
    const int f32 = *dflag;
    const int n = blockIdx.x * 256 + threadIdx.x;
    const int v = blockIdx.y;
    float s = ldf(bias, n, f32);
    for (int k = 0; k < K; k++) s += ldf(E, (long)v * K + k, f32) * ldf(Wi, (long)k * ZDIM + n, f32);
    xz[(long)v * ZDIM + n] = s;
}

// h_dec = hTf + hTb; c_dec = cTf + cTb
__global__ void merge_k(const u16* fhi, const u16* flo, const u16* bhi, const u16* blo,
                        const float* cf, const float* cb,
                        u16* dhi, u16* dlo, float* cd)
{
    const int i = blockIdx.x * 256 + threadIdx.x;
    const float h = bf2f(fhi[i]) + bf2f(flo[i]) + bf2f(bhi[i]) + bf2f(blo[i]);
    const u16 hi = f2bf(h);
    dhi[i] = hi;
    dlo[i] = f2bf(h - bf2f(hi));
    cd[i] = cf[i] + cb[i];
}

struct EncArgs {
    const u16* whT; const u16* whTlo;   // [2048][512] bf16 hi/lo
    const float* xz;                    // [16][2048] fp32
    const int* tokens;                  // [1024][128]
    int rev;                            // 0 fwd, 1 bwd
    u16* fh_hi; u16* fh_lo; float* fc;  // final states [1024][512]
};

// Persistent encoder: 128 blocks (64/dir x 16 rows), all 128 time steps in-kernel.
// h state in LDS (bf16 hi/lo), c state in registers. Only finals stored.
__global__ __launch_bounds__(256, 1) void lstm_enc(EncArgs a0, EncArgs a1)
{
    EncArgs A = (blockIdx.x < 64) ? a0 : a1;
    const int m0 = (blockIdx.x & 63) * MROWS;
    __shared__ u16 shhi[MROWS][PADK];
    __shared__ u16 shlo[MROWS][PADK];
    const int wave = threadIdx.x >> 6, lane = threadIdx.x & 63;
    const int ll = lane & 15, quad = lane >> 4;
    const int wcol0 = wave * 128;                 // gate-local col base for this wave

    for (int i = threadIdx.x; i < MROWS * PADK; i += 256) {
        (&shhi[0][0])[i] = 0; (&shlo[0][0])[i] = 0;
    }
    float c[32];
#pragma unroll
    for (int i = 0; i < 32; i++) c[i] = 0.f;
    __syncthreads();

    const u16* bph = A.whT   + (long)(wcol0 + ll) * HDIM + quad * 8;
    const u16* bpl = A.whTlo + (long)(wcol0 + ll) * HDIM + quad * 8;

#pragma unroll 1
    for (int t = 0; t < S_LEN; t++) {
        const int tt = A.rev ? (S_LEN - 1 - t) : t;
        f32x4 acc[4][8];
#pragma unroll
        for (int g = 0; g < 4; g++)
#pragma unroll
            for (int nt = 0; nt < 8; nt++) acc[g][nt] = (f32x4){0.f, 0.f, 0.f, 0.f};

#pragma unroll 1
        for (int k0 = 0; k0 < HDIM; k0 += 32) {
            const int ko = k0 + quad * 8;
            bf16x8 ahi = *reinterpret_cast<const bf16x8*>(&shhi[ll][ko]);
            bf16x8 alo = *reinterpret_cast<const bf16x8*>(&shlo[ll][ko]);
#pragma unroll
            for (int g = 0; g < 4; g++) {
#pragma unroll
                for (int nt = 0; nt < 8; nt++) {
                    const long off = (long)(g * 512 + nt * 16) * HDIM + k0;
                    bf16x8 bh = *reinterpret_cast<const bf16x8*>(bph + off);
                    bf16x8 bl = *reinterpret_cast<const bf16x8*>(bpl + off);
                    acc[g][nt] = __builtin_amdgcn_mfma_f32_16x16x32_bf16(ahi, bh, acc[g][nt], 0, 0, 0);
                    acc[g][nt] = __builtin_amdgcn_mfma_f32_16x16x32_bf16(alo, bh, acc[g][nt], 0, 0, 0);
                    acc[g][nt] = __builtin_amdgcn_mfma_f32_16x16x32_bf16(ahi, bl, acc[g][nt], 0, 0, 0);
                }
            }
        }
        __syncthreads();   // all waves done reading h

        int vr[4];
#pragma unroll
        for (int r = 0; r < 4; r++) vr[r] = A.tokens[(m0 + quad * 4 + r) * S_LEN + tt];

#pragma unroll
        for (int nt = 0; nt < 8; nt++) {
            const int colg = wcol0 + nt * 16 + ll;
#pragma unroll
            for (int r = 0; r < 4; r++) {
                const int row = quad * 4 + r;
                const float* xzr = A.xz + (long)vr[r] * ZDIM;
                const float zi = acc[0][nt][r] + xzr[colg];
                const float zf = acc[1][nt][r] + xzr[512 + colg];
                const float zg = acc[2][nt][r] + xzr[1024 + colg];
                const float zo = acc[3][nt][r] + xzr[1536 + colg];
                const float c2 = sigm(zf) * c[nt * 4 + r] + sigm(zi) * tanhf(zg);
                const float h2 = sigm(zo) * tanhf(c2);
                c[nt * 4 + r] = c2;
                const u16 hi = f2bf(h2);
                const u16 lo = f2bf(h2 - bf2f(hi));
                shhi[row][colg] = hi;
                shlo[row][colg] = lo;
                if (t == S_LEN - 1) {
                    const long o = (long)(m0 + row) * HDIM + colg;
                    A.fh_hi[o] = hi; A.fh_lo[o] = lo; A.fc[o] = c2;
                }
            }
        }
        __syncthreads();
    }
}

struct DecArgs {
    const u16* whT; const u16* whTlo;
    const float* ez;                    // [9][2048]
    const u16* h0hi; const u16* h0lo; const float* c0;
    const void* Wout; const void* bout;
    void* out; const int* dflag;
};

// Persistent decoder: 64 blocks x 16 rows; 48 greedy steps fully in-kernel.
// LSTM step (MFMA) + logits + softmax + argmax feedback all block-local.
__global__ __launch_bounds__(256, 1) void lstm_dec(DecArgs A)
{
    __shared__ u16 shhi[MROWS][PADK];
    __shared__ u16 shlo[MROWS][PADK];
    __shared__ float Ws[HDIM * OUTV];   // W_out staged fp32
    __shared__ float bs[OUTV];
    __shared__ int ys[MROWS];
    const int m0 = blockIdx.x * MROWS;
    const int wave = threadIdx.x >> 6, lane = threadIdx.x & 63;
    const int ll = lane & 15, quad = lane >> 4;
    const int wcol0 = wave * 128;
    const int f32o = *A.dflag;

    for (int i = threadIdx.x; i < MROWS * HDIM; i += 256) {
        const int r = i >> 9, cl = i & 511;
        shhi[r][cl] = A.h0hi[(long)(m0 + r) * HDIM + cl];
        shlo[r][cl] = A.h0lo[(long)(m0 + r) * HDIM + cl];
    }
    for (int i = threadIdx.x; i < HDIM * OUTV; i += 256) Ws[i] = ldf(A.Wout, i, f32o);
    if (threadIdx.x < OUTV) bs[threadIdx.x] = ldf(A.bout, threadIdx.x, f32o);
    if (threadIdx.x < MROWS) ys[threadIdx.x] = 0;
    float c[32];
#pragma unroll
    for (int nt = 0; nt < 8; nt++)
#pragma unroll
        for (int r = 0; r < 4; r++)
            c[nt * 4 + r] = A.c0[(long)(m0 + quad * 4 + r) * HDIM + wcol0 + nt * 16 + ll];
    __syncthreads();

    const u16* bph = A.whT   + (long)(wcol0 + ll) * HDIM + quad * 8;
    const u16* bpl = A.whTlo + (long)(wcol0 + ll) * HDIM + quad * 8;

#pragma unroll 1
    for (int t = 0; t < MAXLEN; t++) {
        f32x4 acc[4][8];
#pragma unroll
        for (int g = 0; g < 4; g++)
#pragma unroll
            for (int nt = 0; nt < 8; nt++) acc[g][nt] = (f32x4){0.f, 0.f, 0.f, 0.f};

#pragma unroll 1
        for (int k0 = 0; k0 < HDIM; k0 += 32) {
            const int ko = k0 + quad * 8;
            bf16x8 ahi = *reinterpret_cast<const bf16x8*>(&shhi[ll][ko]);
            bf16x8 alo = *reinterpret_cast<const bf16x8*>(&shlo[ll][ko]);
#pragma unroll
            for (int g = 0; g < 4; g++) {
#pragma unroll
                for (int nt = 0; nt < 8; nt++) {
                    const long off = (long)(g * 512 + nt * 16) * HDIM + k0;
                    bf16x8 bh = *reinterpret_cast<const bf16x8*>(bph + off);
                    bf16x8 bl = *reinterpret_cast<const bf16x8*>(bpl + off);
                    acc[g][nt] = __builtin_amdgcn_mfma_f32_16x16x32_bf16(ahi, bh, acc[g][nt], 0, 0, 0);
                    acc[g][nt] = __builtin_amdgcn_mfma_f32_16x16x32_bf16(alo, bh, acc[g][nt], 0, 0, 0);
                    acc[g][nt] = __builtin_amdgcn_mfma_f32_16x16x32_bf16(ahi, bl, acc[g][nt], 0, 0, 0);
                }
            }
        }
        __syncthreads();   // h reads done; ys from previous logits now safe to use

        int vr[4];
#pragma unroll
        for (int r = 0; r < 4; r++) vr[r] = ys[quad * 4 + r];

#pragma unroll
        for (int nt = 0; nt < 8; nt++) {
            const int colg = wcol0 + nt * 16 + ll;
#pragma unroll
            for (int r = 0; r < 4; r++) {
                const int row = quad * 4 + r;
                const float* xzr = A.ez + (long)vr[r] * ZDIM;
                const float zi = acc[0][nt][r] + xzr[colg];
                const float zf = acc[1][nt][r] + xzr[512 + colg];
                const float zg = acc[2][nt][r] + xzr[1024 + colg];
                const float zo = acc[3][nt][r] + xzr[1536 + colg];
                const float c2 = sigm(zf) * c[nt * 4 + r] + sigm(zi) * tanhf(zg);
                const float h2 = sigm(zo) * tanhf(c2);
                c[nt * 4 + r] = c2;
                const u16 hi = f2bf(h2);
                shhi[row][colg] = hi;
                shlo[row][colg] = f2bf(h2 - bf2f(hi));
            }
        }
        __syncthreads();   // h2 visible for logits

        // logits: 16 threads per row, each covers 32 K-elems
        const int row = threadIdx.x >> 4, seg = threadIdx.x & 15;
        const int kb = seg * 32;
        float s[9];
#pragma unroll
        for (int n = 0; n < 9; n++) s[n] = 0.f;
        for (int kk = 0; kk < 32; kk++) {
            const float hv = bf2f(shhi[row][kb + kk]) + bf2f(shlo[row][kb + kk]);
#pragma unroll
            for (int n = 0; n < 9; n++) s[n] += hv * Ws[(kb + kk) * OUTV + n];
        }
#pragma unroll
        for (int n = 0; n < 9; n++) {
            s[n] += __shfl_xor(s[n], 1);
            s[n] += __shfl_xor(s[n], 2);
            s[n] += __shfl_xor(s[n], 4);
            s[n] += __shfl_xor(s[n], 8);
        }
        if (seg == 0) {
            float mx = -1e30f;
#pragma unroll
            for (int n = 0; n < 9; n++) { s[n] += bs[n]; mx = fmaxf(mx, s[n]); }
            float e[9]; float sum = 0.f;
#pragma unroll
            for (int n = 0; n < 9; n++) { e[n] = expf(s[n] - mx); sum += e[n]; }
            const float inv = 1.0f / sum;
            int best = 0; float bv = s[0];
#pragma unroll
            for (int n = 1; n < 9; n++) if (s[n] > bv) { bv = s[n]; best = n; }
            ys[row] = best;
            const long ob = (long)(m0 + row) * (MAXLEN * OUTV) + (long)t * OUTV;
            if (f32o) {
#pragma unroll
                for (int n = 0; n < 9; n++) ((float*)A.out)[ob + n] = e[n] * inv;
            } else {
#pragma unroll
                for (int n = 0; n < 9; n++) ((u16*)A.out)[ob + n] = f2bf(e[n] * inv);
            }
        }
        // no sync needed here: next iteration's post-K sync orders ys/h accesses
    }
}

extern "C" void kernel_launch(void* const* d_in, const int* in_sizes, int n_in,
                              void* d_out, int out_size, void* d_ws, size_t ws_size,
                              hipStream_t stream)
{
    const int* tokens   = (const int*)d_in[0];
    const void* emb_in  = d_in[1];
    const void* Wi_f    = d_in[2];
    const void* Wh_f    = d_in[3];
    const void* b_f     = d_in[4];
    const void* Wi_b    = d_in[5];
    const void* Wh_b    = d_in[6];
    const void* b_b     = d_in[7];
    const void* emb_out = d_in[8];
    const void* Wi_d    = d_in[9];
    const void* Wh_d    = d_in[10];
    const void* b_d     = d_in[11];
    const void* W_out   = d_in[12];
    const void* b_out   = d_in[13];

    char* w = (char*)d_ws;
    auto alloc = [&](size_t bytes) -> char* {
        char* p = w; w += (bytes + 255) & ~((size_t)255); return p;
    };
    int* dflag    = (int*)alloc(256);
    float* xz_f   = (float*)alloc((size_t)INV * ZDIM * 4);
    float* xz_b   = (float*)alloc((size_t)INV * ZDIM * 4);
    float* ez     = (float*)alloc((size_t)OUTV * ZDIM * 4);
    u16* WhT_f    = (u16*)alloc((size_t)ZDIM * HDIM * 2);
    u16* WhTlo_f  = (u16*)alloc((size_t)ZDIM * HDIM * 2);
    u16* WhT_b    = (u16*)alloc((size_t)ZDIM * HDIM * 2);
    u16* WhTlo_b  = (u16*)alloc((size_t)ZDIM * HDIM * 2);
    u16* WhT_d    = (u16*)alloc((size_t)ZDIM * HDIM * 2);
    u16* WhTlo_d  = (u16*)alloc((size_t)ZDIM * HDIM * 2);
    u16* fh_hi    = (u16*)alloc((size_t)B_SZ * HDIM * 2);
    u16* fh_lo    = (u16*)alloc((size_t)B_SZ * HDIM * 2);
    float* fc     = (float*)alloc((size_t)B_SZ * HDIM * 4);
    u16* bh_hi    = (u16*)alloc((size_t)B_SZ * HDIM * 2);
    u16* bh_lo    = (u16*)alloc((size_t)B_SZ * HDIM * 2);
    float* bc     = (float*)alloc((size_t)B_SZ * HDIM * 4);
    u16* dh_hi    = (u16*)alloc((size_t)B_SZ * HDIM * 2);
    u16* dh_lo    = (u16*)alloc((size_t)B_SZ * HDIM * 2);
    float* dc     = (float*)alloc((size_t)B_SZ * HDIM * 4);

    // ---- dtype probe + one-time precompute ----
    detect_k<<<1, 256, 0, stream>>>((const u16*)Wh_f, dflag);
    transpose_k<<<dim3(64, 16), 256, 0, stream>>>(Wh_f, WhT_f, WhTlo_f, dflag);
    transpose_k<<<dim3(64, 16), 256, 0, stream>>>(Wh_b, WhT_b, WhTlo_b, dflag);
    transpose_k<<<dim3(64, 16), 256, 0, stream>>>(Wh_d, WhT_d, WhTlo_d, dflag);
    precompute_xz<<<dim3(8, INV), 256, 0, stream>>>(emb_in, Wi_f, b_f, xz_f, HDIM, dflag);
    precompute_xz<<<dim3(8, INV), 256, 0, stream>>>(emb_in, Wi_b, b_b, xz_b, HDIM, dflag);
    precompute_xz<<<dim3(8, OUTV), 256, 0, stream>>>(emb_out, Wi_d, b_d, ez, OUTV, dflag);

    // ---- persistent bi-directional encoder (1 launch, 128 steps) ----
    EncArgs ef { WhT_f, WhTlo_f, xz_f, tokens, 0, fh_hi, fh_lo, fc };
    EncArgs eb { WhT_b, WhTlo_b, xz_b, tokens, 1, bh_hi, bh_lo, bc };
    lstm_enc<<<dim3(128), 256, 0, stream>>>(ef, eb);

    // ---- merge final states ----
    merge_k<<<dim3((B_SZ * HDIM) / 256), 256, 0, stream>>>(
        fh_hi, fh_lo, bh_hi, bh_lo, fc, bc, dh_hi, dh_lo, dc);

    // ---- persistent greedy decoder (1 launch, 48 steps) ----
    DecArgs da { WhT_d, WhTlo_d, ez, dh_hi, dh_lo, dc, W_out, b_out, d_out, dflag };
    lstm_dec<<<dim3(64), 256, 0, stream>>>(da);
}

// Round 11
// 22099.411 us; speedup vs baseline: 1.2120x; 1.2120x over previous
//
#include <hip/hip_runtime.h>

#define B_SZ 1024
#define S_LEN 128
#define HDIM 512
#define ZDIM 2048   // 4*H
#define INV 16
#define OUTV 9
#define MAXLEN 48
#define MROWS 16    // batch rows per persistent block
#define PADK 520    // padded LDS row stride (u16)

typedef unsigned short u16;
typedef __bf16 bf16x8 __attribute__((ext_vector_type(8)));
typedef float f32x4 __attribute__((ext_vector_type(4)));

__device__ __forceinline__ float bf2f(u16 u) {
    union { float f; unsigned int i; } x; x.i = ((unsigned int)u) << 16; return x.f;
}
__device__ __forceinline__ u16 f2bf(float f) {
    union { float f; unsigned int i; } x; x.f = f;
    unsigned int r = (x.i + 0x7fffu + ((x.i >> 16) & 1u)) >> 16;
    return (u16)r;
}
__device__ __forceinline__ float ldf(const void* p, long i, int isf32) {
    return isf32 ? ((const float*)p)[i] : bf2f(((const u16*)p)[i]);
}
__device__ __forceinline__ float sigm(float x) { return 1.0f / (1.0f + expf(-x)); }
#define MFMA16(a, b, c) __builtin_amdgcn_mfma_f32_16x16x32_bf16((a), (b), (c), 0, 0, 0)

// ---------- preamble ----------
__global__ void detect_k(const u16* __restrict__ wh, int* __restrict__ flag)
{
    __shared__ int s;
    if (threadIdx.x == 0) s = 0;
    __syncthreads();
    int any = 0;
    for (int i = threadIdx.x; i < 16384; i += 256)
        if (((wh[i] >> 7) & 0xFF) >= 0x7F) any = 1;
    if (any) atomicOr(&s, 1);
    __syncthreads();
    if (threadIdx.x == 0) *flag = s;
}

__global__ void transpose_k(const void* __restrict__ src, u16* __restrict__ dhi,
                            u16* __restrict__ dlo, const int* __restrict__ dflag)
{
    __shared__ float tile[32][33];
    const int f32 = *dflag;
    const int tx = threadIdx.x & 31, ty = threadIdx.x >> 5;
    const int n0 = blockIdx.x * 32;
    const int k0 = blockIdx.y * 32;
#pragma unroll
    for (int i = 0; i < 32; i += 8)
        tile[ty + i][tx] = ldf(src, (long)(k0 + ty + i) * ZDIM + n0 + tx, f32);
    __syncthreads();
#pragma unroll
    for (int i = 0; i < 32; i += 8) {
        const float v = tile[tx][ty + i];
        const u16 hi = f2bf(v);
        const long o = (long)(n0 + ty + i) * HDIM + k0 + tx;
        dhi[o] = hi;
        dlo[o] = f2bf(v - bf2f(hi));
    }
}

__global__ void precompute_xz(const void* __restrict__ E, const void* __restrict__ Wi,
                              const void* __restrict__ bias, float* __restrict__ xz,
                              int K, const int* __restrict__ dflag)
{
    const int f32 = *dflag;
    const int n = blockIdx.x * 256 + threadIdx.x;
    const int v = blockIdx.y;
    float s = ldf(bias, n, f32);
    for (int k = 0; k < K; k++) s += ldf(E, (long)v * K + k, f32) * ldf(Wi, (long)k * ZDIM + n, f32);
    xz[(long)v * ZDIM + n] = s;
}

__global__ void merge_k(const u16* fhi, const u16* flo, const u16* bhi, const u16* blo,
                        const float* cf, const float* cb,
                        u16* dhi, u16* dlo, float* cd)
{
    const int i = blockIdx.x * 256 + threadIdx.x;
    const float h = bf2f(fhi[i]) + bf2f(flo[i]) + bf2f(bhi[i]) + bf2f(blo[i]);
    const u16 hi = f2bf(h);
    dhi[i] = hi;
    dlo[i] = f2bf(h - bf2f(hi));
    cd[i] = cf[i] + cb[i];
}

struct EncArgs {
    const u16* whT; const u16* whTlo;   // [2048][512] bf16 hi/lo
    const float* xz;                    // [16][2048] fp32
    const int* tokens;                  // [1024][128]
    int rev;
    u16* fh_hi; u16* fh_lo; float* fc;  // final states [1024][512]
};

// Persistent encoder: 128 blocks x 512 thr. dir = blockIdx&1 (XCD-pure: each
// XCD's L2 caches exactly one dir's 4MB weights). Block = 16 rows, all cols;
// wave = 64 h-cols (acc[4][4]). h in LDS, c in regs. Arithmetic identical to r8.
__global__ __launch_bounds__(512) void lstm_enc(EncArgs a0, EncArgs a1)
{
    const EncArgs A = (blockIdx.x & 1) ? a1 : a0;
    const int m0 = (blockIdx.x >> 1) * MROWS;
    __shared__ u16 shhi[MROWS][PADK];
    __shared__ u16 shlo[MROWS][PADK];
    const int wave = threadIdx.x >> 6, lane = threadIdx.x & 63;
    const int ll = lane & 15, quad = lane >> 4;
    const int wcol0 = wave * 64;                  // gate-local col base (8 waves x 64)

    for (int i = threadIdx.x; i < MROWS * PADK; i += 512) {
        (&shhi[0][0])[i] = 0; (&shlo[0][0])[i] = 0;
    }
    float c[16];
#pragma unroll
    for (int i = 0; i < 16; i++) c[i] = 0.f;
    __syncthreads();

    const u16* bph = A.whT   + (long)(wcol0 + ll) * HDIM + quad * 8;
    const u16* bpl = A.whTlo + (long)(wcol0 + ll) * HDIM + quad * 8;

#pragma unroll 1
    for (int t = 0; t < S_LEN; t++) {
        const int tt = A.rev ? (S_LEN - 1 - t) : t;
        f32x4 acc[4][4];
#pragma unroll
        for (int g = 0; g < 4; g++)
#pragma unroll
            for (int nt = 0; nt < 4; nt++) acc[g][nt] = (f32x4){0.f, 0.f, 0.f, 0.f};

#pragma unroll 1
        for (int k0 = 0; k0 < HDIM; k0 += 32) {
            const int ko = k0 + quad * 8;
            bf16x8 ahi = *reinterpret_cast<const bf16x8*>(&shhi[ll][ko]);
            bf16x8 alo = *reinterpret_cast<const bf16x8*>(&shlo[ll][ko]);
#pragma unroll
            for (int g = 0; g < 4; g++) {
#pragma unroll
                for (int nt = 0; nt < 4; nt++) {
                    const long off = (long)(g * 512 + nt * 16) * HDIM + k0;
                    bf16x8 bh = *reinterpret_cast<const bf16x8*>(bph + off);
                    bf16x8 bl = *reinterpret_cast<const bf16x8*>(bpl + off);
                    acc[g][nt] = MFMA16(ahi, bh, acc[g][nt]);
                    acc[g][nt] = MFMA16(alo, bh, acc[g][nt]);
                    acc[g][nt] = MFMA16(ahi, bl, acc[g][nt]);
                }
            }
        }
        __syncthreads();   // all waves done reading h

        int vr[4];
#pragma unroll
        for (int r = 0; r < 4; r++) vr[r] = A.tokens[(m0 + quad * 4 + r) * S_LEN + tt];

#pragma unroll
        for (int nt = 0; nt < 4; nt++) {
            const int colg = wcol0 + nt * 16 + ll;
#pragma unroll
            for (int r = 0; r < 4; r++) {
                const int row = quad * 4 + r;
                const float* xzr = A.xz + (long)vr[r] * ZDIM;
                const float zi = acc[0][nt][r] + xzr[colg];
                const float zf = acc[1][nt][r] + xzr[512 + colg];
                const float zg = acc[2][nt][r] + xzr[1024 + colg];
                const float zo = acc[3][nt][r] + xzr[1536 + colg];
                const float c2 = sigm(zf) * c[nt * 4 + r] + sigm(zi) * tanhf(zg);
                const float h2 = sigm(zo) * tanhf(c2);
                c[nt * 4 + r] = c2;
                const u16 hi = f2bf(h2);
                const u16 lo = f2bf(h2 - bf2f(hi));
                shhi[row][colg] = hi;
                shlo[row][colg] = lo;
                if (t == S_LEN - 1) {
                    const long o = (long)(m0 + row) * HDIM + colg;
                    A.fh_hi[o] = hi; A.fh_lo[o] = lo; A.fc[o] = c2;
                }
            }
        }
        __syncthreads();
    }
}

struct DecArgs {
    const u16* whT; const u16* whTlo;
    const float* ez;                    // [9][2048]
    const u16* h0hi; const u16* h0lo; const float* c0;
    const void* Wout; const void* bout;
    void* out; const int* dflag;
};

// Persistent decoder: 64 blocks x 512 thr x 16 rows; 48 greedy steps in-kernel.
// Same wave layout as encoder. Logits scalar fp32 (r8 numerics) with
// bank-conflict-free W layout: Wst[(kk*16+seg)*9+n], k = seg*32+kk.
__global__ __launch_bounds__(512) void lstm_dec(DecArgs A)
{
    __shared__ u16 shhi[MROWS][PADK];
    __shared__ u16 shlo[MROWS][PADK];
    __shared__ float Wst[HDIM * OUTV];
    __shared__ float bs[OUTV];
    __shared__ int ys[MROWS];
    const int m0 = blockIdx.x * MROWS;
    const int wave = threadIdx.x >> 6, lane = threadIdx.x & 63;
    const int ll = lane & 15, quad = lane >> 4;
    const int wcol0 = wave * 64;
    const int f32o = *A.dflag;

    for (int i = threadIdx.x; i < MROWS * HDIM; i += 512) {
        const int r = i >> 9, cl = i & 511;
        shhi[r][cl] = A.h0hi[(long)(m0 + r) * HDIM + cl];
        shlo[r][cl] = A.h0lo[(long)(m0 + r) * HDIM + cl];
    }
    for (int i = threadIdx.x; i < HDIM * OUTV; i += 512) {
        const int k = i / 9, n = i - k * 9;
        Wst[((k & 31) * 16 + (k >> 5)) * 9 + n] = ldf(A.Wout, i, f32o);
    }
    if (threadIdx.x < OUTV) bs[threadIdx.x] = ldf(A.bout, threadIdx.x, f32o);
    if (threadIdx.x < MROWS) ys[threadIdx.x] = 0;
    float c[16];
#pragma unroll
    for (int nt = 0; nt < 4; nt++)
#pragma unroll
        for (int r = 0; r < 4; r++)
            c[nt * 4 + r] = A.c0[(long)(m0 + quad * 4 + r) * HDIM + wcol0 + nt * 16 + ll];
    __syncthreads();

    const u16* bph = A.whT   + (long)(wcol0 + ll) * HDIM + quad * 8;
    const u16* bpl = A.whTlo + (long)(wcol0 + ll) * HDIM + quad * 8;

#pragma unroll 1
    for (int t = 0; t < MAXLEN; t++) {
        f32x4 acc[4][4];
#pragma unroll
        for (int g = 0; g < 4; g++)
#pragma unroll
            for (int nt = 0; nt < 4; nt++) acc[g][nt] = (f32x4){0.f, 0.f, 0.f, 0.f};

#pragma unroll 1
        for (int k0 = 0; k0 < HDIM; k0 += 32) {
            const int ko = k0 + quad * 8;
            bf16x8 ahi = *reinterpret_cast<const bf16x8*>(&shhi[ll][ko]);
            bf16x8 alo = *reinterpret_cast<const bf16x8*>(&shlo[ll][ko]);
#pragma unroll
            for (int g = 0; g < 4; g++) {
#pragma unroll
                for (int nt = 0; nt < 4; nt++) {
                    const long off = (long)(g * 512 + nt * 16) * HDIM + k0;
                    bf16x8 bh = *reinterpret_cast<const bf16x8*>(bph + off);
                    bf16x8 bl = *reinterpret_cast<const bf16x8*>(bpl + off);
                    acc[g][nt] = MFMA16(ahi, bh, acc[g][nt]);
                    acc[g][nt] = MFMA16(alo, bh, acc[g][nt]);
                    acc[g][nt] = MFMA16(ahi, bl, acc[g][nt]);
                }
            }
        }
        __syncthreads();   // h reads done; ys now stable

        int vr[4];
#pragma unroll
        for (int r = 0; r < 4; r++) vr[r] = ys[quad * 4 + r];

#pragma unroll
        for (int nt = 0; nt < 4; nt++) {
            const int colg = wcol0 + nt * 16 + ll;
#pragma unroll
            for (int r = 0; r < 4; r++) {
                const int row = quad * 4 + r;
                const float* xzr = A.ez + (long)vr[r] * ZDIM;
                const float zi = acc[0][nt][r] + xzr[colg];
                const float zf = acc[1][nt][r] + xzr[512 + colg];
                const float zg = acc[2][nt][r] + xzr[1024 + colg];
                const float zo = acc[3][nt][r] + xzr[1536 + colg];
                const float c2 = sigm(zf) * c[nt * 4 + r] + sigm(zi) * tanhf(zg);
                const float h2 = sigm(zo) * tanhf(c2);
                c[nt * 4 + r] = c2;
                const u16 hi = f2bf(h2);
                shhi[row][colg] = hi;
                shlo[row][colg] = f2bf(h2 - bf2f(hi));
            }
        }
        __syncthreads();   // h2 visible for logits

        if (threadIdx.x < 256) {
            const int row = threadIdx.x >> 4, seg = threadIdx.x & 15;
            const int kb = seg * 32;
            float s[9];
#pragma unroll
            for (int n = 0; n < 9; n++) s[n] = 0.f;
            for (int kk = 0; kk < 32; kk++) {
                const float hv = bf2f(shhi[row][kb + kk]) + bf2f(shlo[row][kb + kk]);
                const float* wr = &Wst[(kk * 16 + seg) * 9];
#pragma unroll
                for (int n = 0; n < 9; n++) s[n] += hv * wr[n];
            }
#pragma unroll
            for (int n = 0; n < 9; n++) {
                s[n] += __shfl_xor(s[n], 1);
                s[n] += __shfl_xor(s[n], 2);
                s[n] += __shfl_xor(s[n], 4);
                s[n] += __shfl_xor(s[n], 8);
            }
            if (seg == 0) {
                float mx = -1e30f;
#pragma unroll
                for (int n = 0; n < 9; n++) { s[n] += bs[n]; mx = fmaxf(mx, s[n]); }
                float e[9]; float sum = 0.f;
#pragma unroll
                for (int n = 0; n < 9; n++) { e[n] = expf(s[n] - mx); sum += e[n]; }
                const float inv = 1.0f / sum;
                int best = 0; float bv = s[0];
#pragma unroll
                for (int n = 1; n < 9; n++) if (s[n] > bv) { bv = s[n]; best = n; }
                ys[row] = best;
                const long ob = (long)(m0 + row) * (MAXLEN * OUTV) + (long)t * OUTV;
                if (f32o) {
#pragma unroll
                    for (int n = 0; n < 9; n++) ((float*)A.out)[ob + n] = e[n] * inv;
                } else {
#pragma unroll
                    for (int n = 0; n < 9; n++) ((u16*)A.out)[ob + n] = f2bf(e[n] * inv);
                }
            }
        }
        // next iteration's post-K __syncthreads orders ys/h accesses
    }
}

extern "C" void kernel_launch(void* const* d_in, const int* in_sizes, int n_in,
                              void* d_out, int out_size, void* d_ws, size_t ws_size,
                              hipStream_t stream)
{
    const int* tokens   = (const int*)d_in[0];
    const void* emb_in  = d_in[1];
    const void* Wi_f    = d_in[2];
    const void* Wh_f    = d_in[3];
    const void* b_f     = d_in[4];
    const void* Wi_b    = d_in[5];
    const void* Wh_b    = d_in[6];
    const void* b_b     = d_in[7];
    const void* emb_out = d_in[8];
    const void* Wi_d    = d_in[9];
    const void* Wh_d    = d_in[10];
    const void* b_d     = d_in[11];
    const void* W_out   = d_in[12];
    const void* b_out   = d_in[13];

    char* w = (char*)d_ws;
    auto alloc = [&](size_t bytes) -> char* {
        char* p = w; w += (bytes + 255) & ~((size_t)255); return p;
    };
    int* dflag    = (int*)alloc(256);
    float* xz_f   = (float*)alloc((size_t)INV * ZDIM * 4);
    float* xz_b   = (float*)alloc((size_t)INV * ZDIM * 4);
    float* ez     = (float*)alloc((size_t)OUTV * ZDIM * 4);
    u16* WhT_f    = (u16*)alloc((size_t)ZDIM * HDIM * 2);
    u16* WhTlo_f  = (u16*)alloc((size_t)ZDIM * HDIM * 2);
    u16* WhT_b    = (u16*)alloc((size_t)ZDIM * HDIM * 2);
    u16* WhTlo_b  = (u16*)alloc((size_t)ZDIM * HDIM * 2);
    u16* WhT_d    = (u16*)alloc((size_t)ZDIM * HDIM * 2);
    u16* WhTlo_d  = (u16*)alloc((size_t)ZDIM * HDIM * 2);
    u16* fh_hi    = (u16*)alloc((size_t)B_SZ * HDIM * 2);
    u16* fh_lo    = (u16*)alloc((size_t)B_SZ * HDIM * 2);
    float* fc     = (float*)alloc((size_t)B_SZ * HDIM * 4);
    u16* bh_hi    = (u16*)alloc((size_t)B_SZ * HDIM * 2);
    u16* bh_lo    = (u16*)alloc((size_t)B_SZ * HDIM * 2);
    float* bc     = (float*)alloc((size_t)B_SZ * HDIM * 4);
    u16* dh_hi    = (u16*)alloc((size_t)B_SZ * HDIM * 2);
    u16* dh_lo    = (u16*)alloc((size_t)B_SZ * HDIM * 2);
    float* dc     = (float*)alloc((size_t)B_SZ * HDIM * 4);

    // ---- dtype probe + one-time precompute ----
    detect_k<<<1, 256, 0, stream>>>((const u16*)Wh_f, dflag);
    transpose_k<<<dim3(64, 16), 256, 0, stream>>>(Wh_f, WhT_f, WhTlo_f, dflag);
    transpose_k<<<dim3(64, 16), 256, 0, stream>>>(Wh_b, WhT_b, WhTlo_b, dflag);
    transpose_k<<<dim3(64, 16), 256, 0, stream>>>(Wh_d, WhT_d, WhTlo_d, dflag);
    precompute_xz<<<dim3(8, INV), 256, 0, stream>>>(emb_in, Wi_f, b_f, xz_f, HDIM, dflag);
    precompute_xz<<<dim3(8, INV), 256, 0, stream>>>(emb_in, Wi_b, b_b, xz_b, HDIM, dflag);
    precompute_xz<<<dim3(8, OUTV), 256, 0, stream>>>(emb_out, Wi_d, b_d, ez, OUTV, dflag);

    // ---- persistent bi-directional encoder (1 launch, 128 steps) ----
    // dir = blockIdx&1 so each XCD (blockIdx%8) caches only one dir's 4MB weights
    EncArgs ef { WhT_f, WhTlo_f, xz_f, tokens, 0, fh_hi, fh_lo, fc };
    EncArgs eb { WhT_b, WhTlo_b, xz_b, tokens, 1, bh_hi, bh_lo, bc };
    lstm_enc<<<dim3(128), 512, 0, stream>>>(ef, eb);

    // ---- merge final states ----
    merge_k<<<dim3((B_SZ * HDIM) / 256), 256, 0, stream>>>(
        fh_hi, fh_lo, bh_hi, bh_lo, fc, bc, dh_hi, dh_lo, dc);

    // ---- persistent greedy decoder (1 launch, 48 steps) ----
    DecArgs da { WhT_d, WhTlo_d, ez, dh_hi, dh_lo, dc, W_out, b_out, d_out, dflag };
    lstm_dec<<<dim3(64), 512, 0, stream>>>(da);
}